// Round 13
// baseline (264.350 us; speedup 1.0000x reference)
//
#include <hip/hip_runtime.h>
#include <hip/hip_bf16.h>

// TreeLSTM on MI355X — MFMA formulation, round 13.
// 128 trees, heap layout, TREE_SIZE=511, depth 9; children of heap h: 2h+1, 2h+2.
// Gates GEMM: A-row = [x | h0 | h1] (K=384; Ui in both h-ranges via linearity)
//   @ B (384x640), col blocks [i|o|u|f0|f1].
// Zero-LDS gemm levels (R12) + NEW: MI m-subtiles per wave (MI=4 -> 64 nodes/wave)
//   so register-resident b-frags are reused 4x -> B L2 traffic halves vs R12.
// Gate-aligned tiles: lane owns all 5 gates of its feature -> register epilogue.
// Both layers per dispatch. Chain: pack -> leaf -> d7 -> d6 -> d5 -> tail.

#define TS 511
#define NT 128
#define NN (NT * TS)   // 65408

typedef __attribute__((ext_vector_type(8))) short short8;
typedef __attribute__((ext_vector_type(4))) float floatx4;

__device__ __forceinline__ unsigned short f2b(float f) {
    return __builtin_bit_cast(unsigned short, __float2bfloat16(f));
}
__device__ __forceinline__ float b2f_u(unsigned short u) {
    unsigned v = (unsigned)u << 16;
    return __builtin_bit_cast(float, v);
}
__device__ __forceinline__ float sig_(float x) { return 1.0f / (1.0f + __expf(-x)); }
__device__ __forceinline__ float tanh_(float x) {
    float a = fabsf(x);
    float t = __expf(-2.0f * a);
    float r = (1.0f - t) / (1.0f + t);
    return copysignf(r, x);
}

// ---------------- weight packing + x conversion ----------------
// Bg2[((l*12+kb)*640 + n)*32 + kp]: K=384. kb0-3: x (Wi/Wf/Wf). kb4-7: h0 (Ui/Uf/0).
//   kb8-11: h1 (Ui/0/Uf).
// BgU/BgX[(l*512+col)*128+kp]: tail col-major U/X parts.
// bp5[(l*5+g)*128+o]: biases. xb16[node*128+k]: feat converted to bf16.
__global__ void pack_b(const float* __restrict__ Wiou, const float* __restrict__ biou,
                       const float* __restrict__ Uiou, const float* __restrict__ Wf,
                       const float* __restrict__ bfv, const float* __restrict__ Uf,
                       const float* __restrict__ feat,
                       unsigned short* __restrict__ Bg, unsigned short* __restrict__ BgU,
                       unsigned short* __restrict__ BgX, float* __restrict__ bp5,
                       unsigned short* __restrict__ xb) {
    int tid = blockIdx.x * 256 + threadIdx.x;   // 0..1800191
    if (tid < 1280) {
        int l = tid / 640, r = tid % 640, g = r >> 7, o = r & 127;
        bp5[tid] = (g < 3) ? biou[l * 384 + r] : bfv[l * 128 + o];
    }
    if (tid < 491520) {
        int l = tid / 245760;
        int r = tid % 245760;
        int kb = r / 20480;
        int r2 = r % 20480;
        int n = r2 >> 5, kp = r2 & 31;
        int g = n >> 7, o = n & 127;
        float v = 0.f;
        if (kb < 4) {
            int k = kb * 32 + kp;
            v = (g < 3) ? Wiou[(l * 384 + g * 128 + o) * 128 + k]
                        : Wf[(l * 128 + o) * 128 + k];
        } else if (kb < 8) {
            int k = (kb - 4) * 32 + kp;
            if (g < 3)       v = Uiou[(l * 384 + g * 128 + o) * 128 + k];
            else if (g == 3) v = Uf[(l * 128 + o) * 128 + k];
        } else {
            int k = (kb - 8) * 32 + kp;
            if (g < 3)       v = Uiou[(l * 384 + g * 128 + o) * 128 + k];
            else if (g == 4) v = Uf[(l * 128 + o) * 128 + k];
        }
        Bg[tid] = f2b(v);
    } else if (tid < 622592) {
        int e2 = tid - 491520;                 // U-part, < 131072
        int l = e2 >> 16, r = e2 & 65535, col = r >> 7, kp = r & 127;
        float v = (col < 384) ? Uiou[(l * 384 + col) * 128 + kp]
                              : Uf[(l * 128 + (col - 384)) * 128 + kp];
        BgU[((size_t)(l * 512 + col)) * 128 + kp] = f2b(v);
    } else if (tid < 753664) {
        int e2 = tid - 622592;                 // X-part, < 131072
        int l = e2 >> 16, r = e2 & 65535, col = r >> 7, kp = r & 127;
        float v = (col < 384) ? Wiou[(l * 384 + col) * 128 + kp]
                              : Wf[(l * 128 + (col - 384)) * 128 + kp];
        BgX[((size_t)(l * 512 + col)) * 128 + kp] = f2b(v);
    } else {
        int e = tid - 753664;                  // x conversion, < 1046528 (8 elems each)
        size_t base = (size_t)e * 8;
        float4 v0 = *(const float4*)(feat + base);
        float4 v1 = *(const float4*)(feat + base + 4);
        short8 r;
        r[0] = (short)f2b(v0.x); r[1] = (short)f2b(v0.y);
        r[2] = (short)f2b(v0.z); r[3] = (short)f2b(v0.w);
        r[4] = (short)f2b(v1.x); r[5] = (short)f2b(v1.y);
        r[6] = (short)f2b(v1.z); r[7] = (short)f2b(v1.w);
        *(short8*)(xb + base) = r;
    }
}

// ---------------- zero-LDS MFMA level GEMM (d=8..5) ----------------
// 256 threads = 4 waves. Block covers one m-tile of 16*MI nodes; 4 waves split cols.
// Wave computes MI x 16 nodes x gate-aligned tiles ni=g*2+ch at col g*128+wn*32+ch*16.
// b-frags (registers) reused across MI subtiles -> B L2 traffic ~ 1/MI.
template <int NKB, int NI, int MI, bool LEAF>
__global__ __launch_bounds__(256, 2) void gemm_level(
        const unsigned short* __restrict__ xb, const unsigned short* __restrict__ Bg,
        const float* __restrict__ bp5, unsigned short* __restrict__ hb,
        unsigned short* __restrict__ cb, int d, int mshift) {
    const int tid = threadIdx.x;
    const int lane = tid & 63, wave = tid >> 6;
    const int wn = wave;
    const int mt = blockIdx.x;
    const int l = mt >> mshift;
    const int m = mt & ((1 << mshift) - 1);
    const int quad = lane >> 4, l15 = lane & 15;
    unsigned short* h = hb + (size_t)l * NN * 128;
    unsigned short* c = cb + (size_t)l * NN * 128;

    // per-lane A-row node indices (row = l15) for the MI 16-node subtiles
    int nodeA[MI], ch0A[MI];
#pragma unroll
    for (int mi = 0; mi < MI; mi++) {
        int j = m * (16 * MI) + mi * 16 + l15;
        if (LEAF) {
            nodeA[mi] = (j >> 8) * TS + 255 + (j & 255);
            ch0A[mi] = 0;
        } else {
            int tree = j >> d, idx = j & ((1 << d) - 1);
            int heap = (1 << d) - 1 + idx;
            nodeA[mi] = tree * TS + heap;
            ch0A[mi] = tree * TS + 2 * heap + 1;
        }
    }

    floatx4 acc[MI][NI];
#pragma unroll
    for (int mi = 0; mi < MI; mi++)
#pragma unroll
        for (int ni = 0; ni < NI; ni++)
            acc[mi][ni] = (floatx4){0.f, 0.f, 0.f, 0.f};

#pragma unroll
    for (int kb = 0; kb < NKB; kb++) {
        short8 bf[NI];
#pragma unroll
        for (int ni = 0; ni < NI; ni++) {
            const int g = ni >> 1;
            if (!LEAF) {   // structural-zero tiles (compile-time folded)
                if (g == 3 && kb >= 8) continue;
                if (g == 4 && kb >= 4 && kb < 8) continue;
            }
            int col = g * 128 + wn * 32 + (ni & 1) * 16 + l15;
            bf[ni] = *(const short8*)(Bg + ((size_t)(l * 12 + kb) * 640 + col) * 32 + quad * 8);
        }
#pragma unroll
        for (int mi = 0; mi < MI; mi++) {
            const unsigned short* asrc;
            if (LEAF || kb < 4)      asrc = xb + (size_t)nodeA[mi] * 128 + kb * 32;
            else if (kb < 8)         asrc = h + (size_t)ch0A[mi] * 128 + (kb - 4) * 32;
            else                     asrc = h + (size_t)(ch0A[mi] + 1) * 128 + (kb - 8) * 32;
            short8 a = *(const short8*)(asrc + quad * 8);
#pragma unroll
            for (int ni = 0; ni < NI; ni++) {
                const int g = ni >> 1;
                if (!LEAF) {
                    if (g == 3 && kb >= 8) continue;
                    if (g == 4 && kb >= 4 && kb < 8) continue;
                }
                acc[mi][ni] = __builtin_amdgcn_mfma_f32_16x16x32_bf16(a, bf[ni],
                                                                      acc[mi][ni], 0, 0, 0);
            }
        }
    }

    // -------- register epilogue: lane owns gates of features o = wn*32+ch*16+l15
    float bbv[NI];
#pragma unroll
    for (int ni = 0; ni < NI; ni++)
        bbv[ni] = bp5[l * 640 + (ni >> 1) * 128 + wn * 32 + (ni & 1) * 16 + l15];

#pragma unroll
    for (int mi = 0; mi < MI; mi++) {
        int nodes[4];
        unsigned short c0v[4][2], c1v[4][2];
#pragma unroll
        for (int r = 0; r < 4; r++) {
            int j = m * (16 * MI) + mi * 16 + quad * 4 + r;
            if (LEAF) {
                nodes[r] = (j >> 8) * TS + 255 + (j & 255);
            } else {
                int tree = j >> d, idx = j & ((1 << d) - 1);
                int heap = (1 << d) - 1 + idx;
                nodes[r] = tree * TS + heap;
                int ch0 = tree * TS + 2 * heap + 1;
#pragma unroll
                for (int ch = 0; ch < 2; ch++) {
                    int o = wn * 32 + ch * 16 + l15;
                    c0v[r][ch] = c[(size_t)ch0 * 128 + o];
                    c1v[r][ch] = c[(size_t)(ch0 + 1) * 128 + o];
                }
            }
        }
#pragma unroll
        for (int r = 0; r < 4; r++) {
#pragma unroll
            for (int ch = 0; ch < 2; ch++) {
                int o = wn * 32 + ch * 16 + l15;
                float iv = sig_(acc[mi][0 + ch][r] + bbv[0 + ch]);
                float ov = sig_(acc[mi][2 + ch][r] + bbv[2 + ch]);
                float uv = tanh_(acc[mi][4 + ch][r] + bbv[4 + ch]);
                float cn;
                if (LEAF) {
                    cn = iv * uv;
                } else {
                    float f0 = sig_(acc[mi][6 + ch][r] + bbv[6 + ch]);
                    float f1 = sig_(acc[mi][8 + ch][r] + bbv[8 + ch]);
                    cn = iv * uv + f0 * b2f_u(c0v[r][ch]) + f1 * b2f_u(c1v[r][ch]);
                }
                float hn = ov * tanh_(cn);
                h[(size_t)nodes[r] * 128 + o] = f2b(hn);
                c[(size_t)nodes[r] * 128 + o] = f2b(cn);
            }
        }
    }
}

// ---------------- tail: d=4..0 + root out, fully register-resident B ----------------
// 256 blocks = (layer, tree), 512 threads = 8 waves x 80 cols. Unchanged from R12.
__global__ __launch_bounds__(512) void tail_mfma(
        const float* __restrict__ feat, const unsigned short* __restrict__ BgU,
        const unsigned short* __restrict__ BgX, const float* __restrict__ bp5,
        const unsigned short* __restrict__ hb, const unsigned short* __restrict__ cb,
        float* __restrict__ out) {
    __shared__ unsigned short xb[31 * 136];
    __shared__ unsigned short hcH[63 * 136];
    __shared__ unsigned short hcC[63 * 136];
    __shared__ unsigned short Lg[16 * 660];

    const int tid = threadIdx.x;
    const int l = blockIdx.x >> 7, tree = blockIdx.x & 127;
    const int lane = tid & 63, w = tid >> 6;
    const int quad = lane >> 4, l15 = lane & 15;
    const unsigned short* BU = BgU + (size_t)l * 512 * 128;
    const unsigned short* BX = BgX + (size_t)l * 512 * 128;
    const unsigned short* h = hb + (size_t)l * NN * 128;
    const unsigned short* c = cb + (size_t)l * NN * 128;
    const float* bb = bp5 + (size_t)l * 640;

    short8 bfU[5][4], bfX[5][4];
#pragma unroll
    for (int ni = 0; ni < 5; ni++) {
        int gc0 = w * 80 + ni * 16;
        int col = (gc0 < 512) ? gc0 : gc0 - 128;   // f1 cols alias Uf/Wf at col-128
#pragma unroll
        for (int kbl = 0; kbl < 4; kbl++) {
            bfU[ni][kbl] = *(const short8*)(BU + (size_t)(col + l15) * 128 + kbl * 32 + quad * 8);
            bfX[ni][kbl] = *(const short8*)(BX + (size_t)(col + l15) * 128 + kbl * 32 + quad * 8);
        }
    }
    {
        int row = tid >> 4, c8 = (tid & 15) * 8;
        if (row < 31) {
            const float* src = feat + ((size_t)tree * TS + row) * 128 + c8;
            short8 r;
#pragma unroll
            for (int e = 0; e < 8; e++) r[e] = (short)f2b(src[e]);
            *(short8*)(xb + row * 136 + c8) = r;
        }
        *(short8*)(hcH + (31 + row) * 136 + c8) =
            *(const short8*)(h + ((size_t)tree * TS + 31 + row) * 128 + c8);
        *(short8*)(hcC + (31 + row) * 136 + c8) =
            *(const short8*)(c + ((size_t)tree * TS + 31 + row) * 128 + c8);
    }
    __syncthreads();

    for (int dd = 4; dd >= 0; dd--) {
        const int nd = 1 << dd;
        const int rowA = (l15 < nd) ? l15 : nd - 1;   // clamp: extra rows unused
        const int heap = nd - 1 + rowA;
        floatx4 acc[5];
#pragma unroll
        for (int ni = 0; ni < 5; ni++) acc[ni] = (floatx4){0.f, 0.f, 0.f, 0.f};
#pragma unroll
        for (int kbl = 0; kbl < 4; kbl++) {
            int ko = kbl * 32 + quad * 8;
            short8 ax = *(const short8*)(xb + heap * 136 + ko);
            short8 h0 = *(const short8*)(hcH + (2 * heap + 1) * 136 + ko);
            short8 h1 = *(const short8*)(hcH + (2 * heap + 2) * 136 + ko);
            short8 hs;
#pragma unroll
            for (int e = 0; e < 8; e++)
                hs[e] = (short)f2b(b2f_u((unsigned short)h0[e]) +
                                   b2f_u((unsigned short)h1[e]));
#pragma unroll
            for (int ni = 0; ni < 5; ni++) {
                int gc0 = w * 80 + ni * 16;
                short8 a = (gc0 < 384) ? hs : ((gc0 < 512) ? h0 : h1);
                acc[ni] = __builtin_amdgcn_mfma_f32_16x16x32_bf16(ax, bfX[ni][kbl],
                                                                  acc[ni], 0, 0, 0);
                acc[ni] = __builtin_amdgcn_mfma_f32_16x16x32_bf16(a, bfU[ni][kbl],
                                                                  acc[ni], 0, 0, 0);
            }
        }
#pragma unroll
        for (int ni = 0; ni < 5; ni++)
#pragma unroll
            for (int r = 0; r < 4; r++)
                Lg[(quad * 4 + r) * 660 + w * 80 + ni * 16 + l15] = f2b(acc[ni][r]);
        __syncthreads();
        for (int idx = tid; idx < nd * 128; idx += 512) {
            int node = idx >> 7, t = idx & 127;
            int hp = nd - 1 + node;
            const unsigned short* Lr = Lg + node * 660;
            float iv = sig_(b2f_u(Lr[t]) + bb[t]);
            float ov = sig_(b2f_u(Lr[128 + t]) + bb[128 + t]);
            float uv = tanh_(b2f_u(Lr[256 + t]) + bb[256 + t]);
            float f0 = sig_(b2f_u(Lr[384 + t]) + bb[384 + t]);
            float f1 = sig_(b2f_u(Lr[512 + t]) + bb[512 + t]);
            float c0v = b2f_u(hcC[(2 * hp + 1) * 136 + t]);
            float c1v = b2f_u(hcC[(2 * hp + 2) * 136 + t]);
            float cn = iv * uv + f0 * c0v + f1 * c1v;
            float hn = ov * tanh_(cn);
            hcH[hp * 136 + t] = f2b(hn);
            hcC[hp * 136 + t] = f2b(cn);
            if (dd == 0) {
                out[((size_t)l * 128 + tree) * 128 + t] = hn;
                out[32768 + ((size_t)l * 128 + tree) * 128 + t] = cn;
            }
        }
        __syncthreads();
    }
}

extern "C" void kernel_launch(void* const* d_in, const int* in_sizes, int n_in,
                              void* d_out, int out_size, void* d_ws, size_t ws_size,
                              hipStream_t stream) {
    const float* feat = (const float*)d_in[0];
    const float* Wiou = (const float*)d_in[1];
    const float* biou = (const float*)d_in[2];
    const float* Uiou = (const float*)d_in[3];
    const float* Wf   = (const float*)d_in[4];
    const float* bfv  = (const float*)d_in[5];
    const float* Uf   = (const float*)d_in[6];
    float* out = (float*)d_out;

    // ws (bf16 shorts unless noted): h[2][NN*128] c[2][NN*128] Bg2[491520]
    //   BgU[131072] BgX[131072] xb16[NN*128] bp5(f32)[1280]   total ~85 MB
    unsigned short* hb  = (unsigned short*)d_ws;
    unsigned short* cb  = hb + (size_t)2 * NN * 128;
    unsigned short* Bg  = cb + (size_t)2 * NN * 128;
    unsigned short* BgU = Bg + (size_t)491520;
    unsigned short* BgX = BgU + (size_t)131072;
    unsigned short* xb16 = BgX + (size_t)131072;
    float* bp5 = (float*)(xb16 + (size_t)NN * 128);

    pack_b<<<7032, 256, 0, stream>>>(Wiou, biou, Uiou, Wf, bfv, Uf, feat,
                                     Bg, BgU, BgX, bp5, xb16);

    // both layers in every dispatch; zero-LDS streaming GEMMs, MI subtiles per wave
    gemm_level<4, 6, 4, true><<<1024, 256, 0, stream>>>(xb16, Bg, bp5, hb, cb, 0, 9);
    gemm_level<12, 10, 4, false><<<512, 256, 0, stream>>>(xb16, Bg, bp5, hb, cb, 7, 8);
    gemm_level<12, 10, 4, false><<<256, 256, 0, stream>>>(xb16, Bg, bp5, hb, cb, 6, 7);
    gemm_level<12, 10, 2, false><<<256, 256, 0, stream>>>(xb16, Bg, bp5, hb, cb, 5, 7);
    tail_mfma<<<256, 512, 0, stream>>>(feat, BgU, BgX, bp5, hb, cb, out);
}

// Round 14
// 243.586 us; speedup vs baseline: 1.0852x; 1.0852x over previous
//
#include <hip/hip_runtime.h>
#include <hip/hip_bf16.h>

// TreeLSTM on MI355X — MFMA formulation, round 14.
// 128 trees, heap layout, TREE_SIZE=511, depth 9; children of heap h: 2h+1, 2h+2.
// Gates GEMM: A-row = [x | h0 | h1] (K=384; Ui in both h-ranges via linearity)
//   @ B (384x640), col blocks [i|o|u|f0|f1].
// Zero-LDS gemm levels; 512-thread blocks = 8 waves; wave owns ONE 16-col chunk
//   per gate (NG tiles) and MI=4 m-subtiles (64 nodes/block) -> b-frags reused 4x
//   with only ~100 live VGPRs (R13's 4-wave MI=4 spilled: VGPR 128 < 160 needed).
// Gate-aligned tiles: lane owns all gates of feature o=wn*16+l15 -> register epilogue.
// Both layers per dispatch. Chain: pack -> leaf -> d7 -> d6 -> d5 -> tail.

#define TS 511
#define NT 128
#define NN (NT * TS)   // 65408

typedef __attribute__((ext_vector_type(8))) short short8;
typedef __attribute__((ext_vector_type(4))) float floatx4;

__device__ __forceinline__ unsigned short f2b(float f) {
    return __builtin_bit_cast(unsigned short, __float2bfloat16(f));
}
__device__ __forceinline__ float b2f_u(unsigned short u) {
    unsigned v = (unsigned)u << 16;
    return __builtin_bit_cast(float, v);
}
__device__ __forceinline__ float sig_(float x) { return 1.0f / (1.0f + __expf(-x)); }
__device__ __forceinline__ float tanh_(float x) {
    float a = fabsf(x);
    float t = __expf(-2.0f * a);
    float r = (1.0f - t) / (1.0f + t);
    return copysignf(r, x);
}

// ---------------- weight packing + x conversion ----------------
// Bg2[((l*12+kb)*640 + n)*32 + kp]: K=384. kb0-3: x (Wi/Wf/Wf). kb4-7: h0 (Ui/Uf/0).
//   kb8-11: h1 (Ui/0/Uf).
// BgU/BgX[(l*512+col)*128+kp]: tail col-major U/X parts.
// bp5[(l*5+g)*128+o]: biases. xb16[node*128+k]: feat converted to bf16.
__global__ void pack_b(const float* __restrict__ Wiou, const float* __restrict__ biou,
                       const float* __restrict__ Uiou, const float* __restrict__ Wf,
                       const float* __restrict__ bfv, const float* __restrict__ Uf,
                       const float* __restrict__ feat,
                       unsigned short* __restrict__ Bg, unsigned short* __restrict__ BgU,
                       unsigned short* __restrict__ BgX, float* __restrict__ bp5,
                       unsigned short* __restrict__ xb) {
    int tid = blockIdx.x * 256 + threadIdx.x;   // 0..1800191
    if (tid < 1280) {
        int l = tid / 640, r = tid % 640, g = r >> 7, o = r & 127;
        bp5[tid] = (g < 3) ? biou[l * 384 + r] : bfv[l * 128 + o];
    }
    if (tid < 491520) {
        int l = tid / 245760;
        int r = tid % 245760;
        int kb = r / 20480;
        int r2 = r % 20480;
        int n = r2 >> 5, kp = r2 & 31;
        int g = n >> 7, o = n & 127;
        float v = 0.f;
        if (kb < 4) {
            int k = kb * 32 + kp;
            v = (g < 3) ? Wiou[(l * 384 + g * 128 + o) * 128 + k]
                        : Wf[(l * 128 + o) * 128 + k];
        } else if (kb < 8) {
            int k = (kb - 4) * 32 + kp;
            if (g < 3)       v = Uiou[(l * 384 + g * 128 + o) * 128 + k];
            else if (g == 3) v = Uf[(l * 128 + o) * 128 + k];
        } else {
            int k = (kb - 8) * 32 + kp;
            if (g < 3)       v = Uiou[(l * 384 + g * 128 + o) * 128 + k];
            else if (g == 4) v = Uf[(l * 128 + o) * 128 + k];
        }
        Bg[tid] = f2b(v);
    } else if (tid < 622592) {
        int e2 = tid - 491520;                 // U-part, < 131072
        int l = e2 >> 16, r = e2 & 65535, col = r >> 7, kp = r & 127;
        float v = (col < 384) ? Uiou[(l * 384 + col) * 128 + kp]
                              : Uf[(l * 128 + (col - 384)) * 128 + kp];
        BgU[((size_t)(l * 512 + col)) * 128 + kp] = f2b(v);
    } else if (tid < 753664) {
        int e2 = tid - 622592;                 // X-part, < 131072
        int l = e2 >> 16, r = e2 & 65535, col = r >> 7, kp = r & 127;
        float v = (col < 384) ? Wiou[(l * 384 + col) * 128 + kp]
                              : Wf[(l * 128 + (col - 384)) * 128 + kp];
        BgX[((size_t)(l * 512 + col)) * 128 + kp] = f2b(v);
    } else {
        int e = tid - 753664;                  // x conversion, < 1046528 (8 elems each)
        size_t base = (size_t)e * 8;
        float4 v0 = *(const float4*)(feat + base);
        float4 v1 = *(const float4*)(feat + base + 4);
        short8 r;
        r[0] = (short)f2b(v0.x); r[1] = (short)f2b(v0.y);
        r[2] = (short)f2b(v0.z); r[3] = (short)f2b(v0.w);
        r[4] = (short)f2b(v1.x); r[5] = (short)f2b(v1.y);
        r[6] = (short)f2b(v1.z); r[7] = (short)f2b(v1.w);
        *(short8*)(xb + base) = r;
    }
}

// ---------------- zero-LDS MFMA level GEMM (d=8..5) ----------------
// 512 threads = 8 waves. Block covers 16*MI nodes; wave wn owns col chunk
// g*128 + wn*16 for each gate g (NG tiles). b-frags reused across MI subtiles.
template <int NKB, int NG, int MI, bool LEAF>
__global__ __launch_bounds__(512) void gemm_level(
        const unsigned short* __restrict__ xb, const unsigned short* __restrict__ Bg,
        const float* __restrict__ bp5, unsigned short* __restrict__ hb,
        unsigned short* __restrict__ cb, int d, int mshift) {
    const int tid = threadIdx.x;
    const int lane = tid & 63, wn = tid >> 6;
    const int mt = blockIdx.x;
    const int l = mt >> mshift;
    const int m = mt & ((1 << mshift) - 1);
    const int quad = lane >> 4, l15 = lane & 15;
    unsigned short* h = hb + (size_t)l * NN * 128;
    unsigned short* c = cb + (size_t)l * NN * 128;

    // per-lane A-row node indices (row = l15) for the MI 16-node subtiles
    int nodeA[MI], ch0A[MI];
#pragma unroll
    for (int mi = 0; mi < MI; mi++) {
        int j = m * (16 * MI) + mi * 16 + l15;
        if (LEAF) {
            nodeA[mi] = (j >> 8) * TS + 255 + (j & 255);
            ch0A[mi] = 0;
        } else {
            int tree = j >> d, idx = j & ((1 << d) - 1);
            int heap = (1 << d) - 1 + idx;
            nodeA[mi] = tree * TS + heap;
            ch0A[mi] = tree * TS + 2 * heap + 1;
        }
    }

    floatx4 acc[MI][NG];
#pragma unroll
    for (int mi = 0; mi < MI; mi++)
#pragma unroll
        for (int g = 0; g < NG; g++)
            acc[mi][g] = (floatx4){0.f, 0.f, 0.f, 0.f};

#pragma unroll
    for (int kb = 0; kb < NKB; kb++) {
        short8 bf[NG];
#pragma unroll
        for (int g = 0; g < NG; g++) {
            if (!LEAF) {   // structural-zero tiles (compile-time folded)
                if (g == 3 && kb >= 8) continue;
                if (g == 4 && kb >= 4 && kb < 8) continue;
            }
            int col = g * 128 + wn * 16 + l15;
            bf[g] = *(const short8*)(Bg + ((size_t)(l * 12 + kb) * 640 + col) * 32 + quad * 8);
        }
#pragma unroll
        for (int mi = 0; mi < MI; mi++) {
            const unsigned short* asrc;
            if (LEAF || kb < 4)      asrc = xb + (size_t)nodeA[mi] * 128 + kb * 32;
            else if (kb < 8)         asrc = h + (size_t)ch0A[mi] * 128 + (kb - 4) * 32;
            else                     asrc = h + (size_t)(ch0A[mi] + 1) * 128 + (kb - 8) * 32;
            short8 a = *(const short8*)(asrc + quad * 8);
#pragma unroll
            for (int g = 0; g < NG; g++) {
                if (!LEAF) {
                    if (g == 3 && kb >= 8) continue;
                    if (g == 4 && kb >= 4 && kb < 8) continue;
                }
                acc[mi][g] = __builtin_amdgcn_mfma_f32_16x16x32_bf16(a, bf[g],
                                                                     acc[mi][g], 0, 0, 0);
            }
        }
    }

    // -------- register epilogue: lane owns gates of feature o = wn*16 + l15
    const int o = wn * 16 + l15;
    float bbv[NG];
#pragma unroll
    for (int g = 0; g < NG; g++)
        bbv[g] = bp5[l * 640 + g * 128 + o];

#pragma unroll
    for (int mi = 0; mi < MI; mi++) {
        int nodes[4];
        unsigned short c0v[4], c1v[4];
#pragma unroll
        for (int r = 0; r < 4; r++) {
            int j = m * (16 * MI) + mi * 16 + quad * 4 + r;
            if (LEAF) {
                nodes[r] = (j >> 8) * TS + 255 + (j & 255);
            } else {
                int tree = j >> d, idx = j & ((1 << d) - 1);
                int heap = (1 << d) - 1 + idx;
                nodes[r] = tree * TS + heap;
                int ch0 = tree * TS + 2 * heap + 1;
                c0v[r] = c[(size_t)ch0 * 128 + o];
                c1v[r] = c[(size_t)(ch0 + 1) * 128 + o];
            }
        }
#pragma unroll
        for (int r = 0; r < 4; r++) {
            float iv = sig_(acc[mi][0][r] + bbv[0]);
            float ov = sig_(acc[mi][1][r] + bbv[1]);
            float uv = tanh_(acc[mi][2][r] + bbv[2]);
            float cn;
            if (LEAF) {
                cn = iv * uv;
            } else {
                float f0 = sig_(acc[mi][3][r] + bbv[3]);
                float f1 = sig_(acc[mi][4][r] + bbv[4]);
                cn = iv * uv + f0 * b2f_u(c0v[r]) + f1 * b2f_u(c1v[r]);
            }
            float hn = ov * tanh_(cn);
            h[(size_t)nodes[r] * 128 + o] = f2b(hn);
            c[(size_t)nodes[r] * 128 + o] = f2b(cn);
        }
    }
}

// ---------------- tail: d=4..0 + root out, fully register-resident B ----------------
// 256 blocks = (layer, tree), 512 threads = 8 waves x 80 cols. Unchanged from R12.
__global__ __launch_bounds__(512) void tail_mfma(
        const float* __restrict__ feat, const unsigned short* __restrict__ BgU,
        const unsigned short* __restrict__ BgX, const float* __restrict__ bp5,
        const unsigned short* __restrict__ hb, const unsigned short* __restrict__ cb,
        float* __restrict__ out) {
    __shared__ unsigned short xb[31 * 136];
    __shared__ unsigned short hcH[63 * 136];
    __shared__ unsigned short hcC[63 * 136];
    __shared__ unsigned short Lg[16 * 660];

    const int tid = threadIdx.x;
    const int l = blockIdx.x >> 7, tree = blockIdx.x & 127;
    const int lane = tid & 63, w = tid >> 6;
    const int quad = lane >> 4, l15 = lane & 15;
    const unsigned short* BU = BgU + (size_t)l * 512 * 128;
    const unsigned short* BX = BgX + (size_t)l * 512 * 128;
    const unsigned short* h = hb + (size_t)l * NN * 128;
    const unsigned short* c = cb + (size_t)l * NN * 128;
    const float* bb = bp5 + (size_t)l * 640;

    short8 bfU[5][4], bfX[5][4];
#pragma unroll
    for (int ni = 0; ni < 5; ni++) {
        int gc0 = w * 80 + ni * 16;
        int col = (gc0 < 512) ? gc0 : gc0 - 128;   // f1 cols alias Uf/Wf at col-128
#pragma unroll
        for (int kbl = 0; kbl < 4; kbl++) {
            bfU[ni][kbl] = *(const short8*)(BU + (size_t)(col + l15) * 128 + kbl * 32 + quad * 8);
            bfX[ni][kbl] = *(const short8*)(BX + (size_t)(col + l15) * 128 + kbl * 32 + quad * 8);
        }
    }
    {
        int row = tid >> 4, c8 = (tid & 15) * 8;
        if (row < 31) {
            const float* src = feat + ((size_t)tree * TS + row) * 128 + c8;
            short8 r;
#pragma unroll
            for (int e = 0; e < 8; e++) r[e] = (short)f2b(src[e]);
            *(short8*)(xb + row * 136 + c8) = r;
        }
        *(short8*)(hcH + (31 + row) * 136 + c8) =
            *(const short8*)(h + ((size_t)tree * TS + 31 + row) * 128 + c8);
        *(short8*)(hcC + (31 + row) * 136 + c8) =
            *(const short8*)(c + ((size_t)tree * TS + 31 + row) * 128 + c8);
    }
    __syncthreads();

    for (int dd = 4; dd >= 0; dd--) {
        const int nd = 1 << dd;
        const int rowA = (l15 < nd) ? l15 : nd - 1;   // clamp: extra rows unused
        const int heap = nd - 1 + rowA;
        floatx4 acc[5];
#pragma unroll
        for (int ni = 0; ni < 5; ni++) acc[ni] = (floatx4){0.f, 0.f, 0.f, 0.f};
#pragma unroll
        for (int kbl = 0; kbl < 4; kbl++) {
            int ko = kbl * 32 + quad * 8;
            short8 ax = *(const short8*)(xb + heap * 136 + ko);
            short8 h0 = *(const short8*)(hcH + (2 * heap + 1) * 136 + ko);
            short8 h1 = *(const short8*)(hcH + (2 * heap + 2) * 136 + ko);
            short8 hs;
#pragma unroll
            for (int e = 0; e < 8; e++)
                hs[e] = (short)f2b(b2f_u((unsigned short)h0[e]) +
                                   b2f_u((unsigned short)h1[e]));
#pragma unroll
            for (int ni = 0; ni < 5; ni++) {
                int gc0 = w * 80 + ni * 16;
                short8 a = (gc0 < 384) ? hs : ((gc0 < 512) ? h0 : h1);
                acc[ni] = __builtin_amdgcn_mfma_f32_16x16x32_bf16(ax, bfX[ni][kbl],
                                                                  acc[ni], 0, 0, 0);
                acc[ni] = __builtin_amdgcn_mfma_f32_16x16x32_bf16(a, bfU[ni][kbl],
                                                                  acc[ni], 0, 0, 0);
            }
        }
#pragma unroll
        for (int ni = 0; ni < 5; ni++)
#pragma unroll
            for (int r = 0; r < 4; r++)
                Lg[(quad * 4 + r) * 660 + w * 80 + ni * 16 + l15] = f2b(acc[ni][r]);
        __syncthreads();
        for (int idx = tid; idx < nd * 128; idx += 512) {
            int node = idx >> 7, t = idx & 127;
            int hp = nd - 1 + node;
            const unsigned short* Lr = Lg + node * 660;
            float iv = sig_(b2f_u(Lr[t]) + bb[t]);
            float ov = sig_(b2f_u(Lr[128 + t]) + bb[128 + t]);
            float uv = tanh_(b2f_u(Lr[256 + t]) + bb[256 + t]);
            float f0 = sig_(b2f_u(Lr[384 + t]) + bb[384 + t]);
            float f1 = sig_(b2f_u(Lr[512 + t]) + bb[512 + t]);
            float c0v = b2f_u(hcC[(2 * hp + 1) * 136 + t]);
            float c1v = b2f_u(hcC[(2 * hp + 2) * 136 + t]);
            float cn = iv * uv + f0 * c0v + f1 * c1v;
            float hn = ov * tanh_(cn);
            hcH[hp * 136 + t] = f2b(hn);
            hcC[hp * 136 + t] = f2b(cn);
            if (dd == 0) {
                out[((size_t)l * 128 + tree) * 128 + t] = hn;
                out[32768 + ((size_t)l * 128 + tree) * 128 + t] = cn;
            }
        }
        __syncthreads();
    }
}

extern "C" void kernel_launch(void* const* d_in, const int* in_sizes, int n_in,
                              void* d_out, int out_size, void* d_ws, size_t ws_size,
                              hipStream_t stream) {
    const float* feat = (const float*)d_in[0];
    const float* Wiou = (const float*)d_in[1];
    const float* biou = (const float*)d_in[2];
    const float* Uiou = (const float*)d_in[3];
    const float* Wf   = (const float*)d_in[4];
    const float* bfv  = (const float*)d_in[5];
    const float* Uf   = (const float*)d_in[6];
    float* out = (float*)d_out;

    // ws (bf16 shorts unless noted): h[2][NN*128] c[2][NN*128] Bg2[491520]
    //   BgU[131072] BgX[131072] xb16[NN*128] bp5(f32)[1280]   total ~85 MB
    unsigned short* hb  = (unsigned short*)d_ws;
    unsigned short* cb  = hb + (size_t)2 * NN * 128;
    unsigned short* Bg  = cb + (size_t)2 * NN * 128;
    unsigned short* BgU = Bg + (size_t)491520;
    unsigned short* BgX = BgU + (size_t)131072;
    unsigned short* xb16 = BgX + (size_t)131072;
    float* bp5 = (float*)(xb16 + (size_t)NN * 128);

    pack_b<<<7032, 256, 0, stream>>>(Wiou, biou, Uiou, Wf, bfv, Uf, feat,
                                     Bg, BgU, BgX, bp5, xb16);

    // both layers per dispatch; 8-wave zero-LDS streaming GEMMs, MI subtiles/wave
    gemm_level<4, 3, 4, true><<<1024, 512, 0, stream>>>(xb16, Bg, bp5, hb, cb, 0, 9);
    gemm_level<12, 5, 4, false><<<512, 512, 0, stream>>>(xb16, Bg, bp5, hb, cb, 7, 8);
    gemm_level<12, 5, 4, false><<<256, 512, 0, stream>>>(xb16, Bg, bp5, hb, cb, 6, 7);
    gemm_level<12, 5, 2, false><<<256, 512, 0, stream>>>(xb16, Bg, bp5, hb, cb, 5, 7);
    tail_mfma<<<256, 512, 0, stream>>>(feat, BgU, BgX, bp5, hb, cb, out);
}